// Round 9
// baseline (700.547 us; speedup 1.0000x reference)
//
#include <hip/hip_runtime.h>

// RepetHead: 4 layers of (3x3 offset conv -> DCNv1 deform conv -> ReLU)
// B=4, C=256, H=W=64, K=9 taps.
// Round 9: deform is DECOMPOSED via linearity of bilinear sampling:
//   out[m][n] = sum_k sum_j cw[k,m,j] * PV[ci[k,m,j]][k][n]
//   PV[pos][k][n] = sum_c w[n][k][c] * x[pos][c]   (dense bf16 MFMA GEMM)
// pvgemm: pure GEMM, A direct from [pos][c] plane (zero-LDS frag loads,
//         zero per-chunk VALU) -> MFMA-bound.
// combine: streaming 36-row weighted sum in fp32, n-vectorized, + ReLU
//         -> memory/VALU streaming, no extract/split/repack storm.
// PV stored bf16-hi per batch image (18.9 MB); plane updated IN PLACE per b
// (combine(b) overwrites exactly the slice pvgemm(b) consumed).
//
// ws layout (floats):
//   offs :   294,912
//   wph  : 1,179,648  (2,359,296 ushort, deform B frag-packed, bf16-hi)
//   owph :   147,456  (  294,912 ushort, offset-conv B frag-packed)
//   xT   : 2,097,152  (4,194,304 ushort, single activation plane, in-place)
//   pvh  : 4,718,592  (9,437,184 ushort, PV[4096][9][256] bf16-hi, per-b)
// total 8,437,760 floats = 33.75 MB (<= 36.8 MB proven in r1/r4)

#define HW 4096

typedef __attribute__((ext_vector_type(8))) __bf16 bf16x8;
typedef __attribute__((ext_vector_type(4))) float f32x4;
typedef __attribute__((ext_vector_type(8))) unsigned short u16x8;

__device__ inline unsigned int f2bf_bits(float f) {
  unsigned int u = __float_as_uint(f);
  return (u + 0x7fffu + ((u >> 16) & 1u)) >> 16;   // RNE to bf16
}
__device__ inline float bf_lo_f(unsigned int w) {   // low ushort -> fp32
  return __uint_as_float(w << 16);
}
__device__ inline float bf_hi_f32(unsigned int w) { // high ushort -> fp32
  return __uint_as_float(w & 0xffff0000u);
}

// ---------------------------------------------------------------------------
// w[r][o][c][ky][kx] -> frag-packed wph[r][q=72][nt=16][lane=64][j=8] (bf16-hi)
// n = nt*16+(lane&15); kk = q*32+(lane>>4)*8+j; c = kk&255; k = kk>>8.
__global__ __launch_bounds__(256) void wpack_kernel(
    const float* __restrict__ w, unsigned short* __restrict__ wph) {
  const int f = blockIdx.x * 256 + threadIdx.x;   // < 2,359,296
  const int j  = f & 7;
  const int l  = (f >> 3) & 63;
  const int nt = (f >> 9) & 15;
  const int q  = (f >> 13) % 72;
  const int r  = f / 589824;
  const int n  = nt * 16 + (l & 15);
  const int kk = q * 32 + ((l >> 4) << 3) + j;
  const int c  = kk & 255, k = kk >> 8;
  wph[f] = (unsigned short)f2bf_bits(w[((r * 256 + n) * 256 + c) * 9 + k]);
}

// offw[r][18][256][3][3] -> owph[r][q=72][nt=2][lane=64][j=8] (n>=18 -> 0)
__global__ __launch_bounds__(256) void offwpack_kernel(
    const float* __restrict__ offw, unsigned short* __restrict__ owph) {
  const int f = blockIdx.x * 256 + threadIdx.x;   // < 294,912
  const int j  = f & 7;
  const int l  = (f >> 3) & 63;
  const int nt = (f >> 9) & 1;
  const int q  = (f >> 10) % 72;
  const int r  = f / 73728;
  const int n  = nt * 16 + (l & 15);
  const int kk = q * 32 + ((l >> 4) << 3) + j;
  const int c  = kk & 255, k = kk >> 8;
  const float v = (n < 18) ? offw[((r * 18 + n) * 256 + c) * 9 + k] : 0.f;
  owph[f] = (unsigned short)f2bf_bits(v);
}

// ---------------------------------------------------------------------------
// x [4][256][4096] fp32 -> xT [4][4096][256] bf16-hi (transpose + cast)
__global__ __launch_bounds__(256) void xpose_kernel(
    const float* __restrict__ x, unsigned short* __restrict__ xh) {
  const int p0 = blockIdx.x * 64;     // pos tile
  const int c0 = blockIdx.y * 64;     // channel tile
  const int b  = blockIdx.z;
  __shared__ float sT[64][65];
  const int t = threadIdx.x;
  const int pj = t & 63, ci0 = (t >> 6) * 16;
  const float* __restrict__ xb = x + ((size_t)(b * 256 + c0)) * HW + p0;
#pragma unroll
  for (int u = 0; u < 16; ++u)
    sT[ci0 + u][pj] = xb[(size_t)(ci0 + u) * HW + pj];
  __syncthreads();
  const int pr = t >> 2, cs = (t & 3) * 16;
  u16x8 va, vb;
#pragma unroll
  for (int u = 0; u < 8; ++u) va[u] = (unsigned short)f2bf_bits(sT[cs + u][pr]);
#pragma unroll
  for (int u = 0; u < 8; ++u) vb[u] = (unsigned short)f2bf_bits(sT[cs + 8 + u][pr]);
  const size_t o = ((size_t)b * HW + p0 + pr) * 256 + c0 + cs;
  *(u16x8*)(xh + o) = va;
  *(u16x8*)(xh + o + 8) = vb;
}

// ---------------------------------------------------------------------------
// Offset conv, zero-LDS MFMA (r4-proven). block = 32m x 32n, 4 waves.
__global__ __launch_bounds__(256) void offconv_mfma(
    const unsigned short* __restrict__ xh,
    const unsigned short* __restrict__ owh,
    const float* __restrict__ bias, float* __restrict__ offs) {
  const int gid = blockIdx.x;                 // 0..511
  const int b = (gid & 7) >> 1;
  const int idx = ((gid >> 3) << 1) | (gid & 1);   // 0..127
  const int h = idx >> 1, w0 = (idx & 1) << 5;
  const int t = threadIdx.x, lane = t & 63, wv = t >> 6;
  const int frow = lane & 15, fgrp = lane >> 4;
  const int mt = wv & 1, nt = wv >> 1;
  const int m = w0 + mt * 16 + frow;          // w coordinate of A row

  f32x4 acc = {0.f, 0.f, 0.f, 0.f};
  const u16x8 z8 = {};
  const size_t xb = (size_t)b * HW;

  for (int k = 0; k < 9; ++k) {
    const int ky = k / 3 - 1, kx = k % 3 - 1;
    if ((unsigned)(h + ky) >= 64u) continue;  // block-uniform: tap row is 0
    const bool vpx = (unsigned)(m + kx) < 64u;
    const int cpx = (m + kx) < 0 ? 0 : ((m + kx) > 63 ? 63 : (m + kx));
    const size_t abase = (xb + (size_t)((h + ky) * 64 + cpx)) * 256 + fgrp * 8;
#pragma unroll
    for (int cc = 0; cc < 8; ++cc) {
      const int q = k * 8 + cc;
      u16x8 ahr = *(const u16x8*)(xh + abase + cc * 32);
      if (!vpx) ahr = z8;
      const u16x8 bhr = ((const u16x8*)owh)[(q * 2 + nt) * 64 + lane];
      const bf16x8 ah = __builtin_bit_cast(bf16x8, ahr);
      const bf16x8 bh = __builtin_bit_cast(bf16x8, bhr);
      acc = __builtin_amdgcn_mfma_f32_16x16x32_bf16(ah, bh, acc, 0, 0, 0);
    }
  }
  const int oc = nt * 16 + frow;              // C/D: col = lane&15 -> n
  if (oc < 18) {
    const float bv = bias[oc];
    const int wbase = w0 + mt * 16 + fgrp * 4;  // C/D: row = (lane>>4)*4 + r
    float* __restrict__ op = offs + (size_t)(b * 18 + oc) * HW + h * 64 + wbase;
#pragma unroll
    for (int r = 0; r < 4; ++r) op[r] = acc[r] + bv;
  }
}

// ---------------------------------------------------------------------------
// PV GEMM (per b): PV[pos][k][n] = sum_c x[pos][c] * w[n][k][c].
// grid (18, 64): blockIdx.x -> (k = x>>1, half = x&1); blockIdx.y = pos tile.
// Block 64 pos x 128 n; wave = 16 pos x 128 n: 8 chunks x (1 A-load + 8 MFMA).
__global__ __launch_bounds__(256) void pvgemm_kernel(
    const unsigned short* __restrict__ xh,   // b-slice [4096][256] bf16-hi
    const unsigned short* __restrict__ wph,  // this layer, [72][16][64][8]
    unsigned short* __restrict__ pvh) {      // [4096][9][256] bf16-hi
  const int nb = blockIdx.x;                 // 0..17
  const int pt = blockIdx.y;                 // 0..63
  const int k = nb >> 1, half = nb & 1;
  const int t = threadIdx.x, lane = t & 63, wv = t >> 6;
  const int frow = lane & 15, quad = lane >> 4;
  const int pos0 = pt * 64 + wv * 16;

  f32x4 acc[8];
#pragma unroll
  for (int nt = 0; nt < 8; ++nt) acc[nt] = (f32x4){0.f, 0.f, 0.f, 0.f};

  const unsigned short* __restrict__ ap =
      xh + (size_t)(pos0 + frow) * 256 + quad * 8;
  const u16x8* __restrict__ wp = (const u16x8*)wph;
  const int qb = k * 8;

#pragma unroll
  for (int cc = 0; cc < 8; ++cc) {
    const bf16x8 a = __builtin_bit_cast(bf16x8, *(const u16x8*)(ap + cc * 32));
#pragma unroll
    for (int nt = 0; nt < 8; ++nt) {
      const bf16x8 bv = __builtin_bit_cast(
          bf16x8, wp[((qb + cc) * 16 + half * 8 + nt) * 64 + lane]);
      acc[nt] = __builtin_amdgcn_mfma_f32_16x16x32_bf16(a, bv, acc[nt], 0, 0, 0);
    }
  }
  // epilogue: C/D row = quad*4+r -> pos, col = frow -> n (within tile)
#pragma unroll
  for (int nt = 0; nt < 8; ++nt) {
#pragma unroll
    for (int r = 0; r < 4; ++r) {
      const int pos = pos0 + quad * 4 + r;
      pvh[((size_t)pos * 9 + k) * 256 + half * 128 + nt * 16 + frow] =
          (unsigned short)f2bf_bits(acc[nt][r]);
    }
  }
}

// ---------------------------------------------------------------------------
// Combine (per b): out[pos][n] = relu( sum_k sum_j cw[k,pos,j] *
//                                      PV[ci[k,pos,j]][k][n] )
// Block = 8 positions, 4 waves (wave = 2 pos x 256 n, lane owns 4 n).
// Layers 0-2: writes the activation plane IN PLACE ([pos][n] bf16-hi).
// Layer 3: fp32 NCHW to d_out via LDS transpose.
__global__ __launch_bounds__(256) void combine_kernel(
    const unsigned short* __restrict__ pvh,  // [4096][9][256] for batch b
    const float* __restrict__ offs,          // [4][18][4096]
    const int b,
    unsigned short* __restrict__ yplane,     // xT b-slice (layers 0-2) or null
    float* __restrict__ outf) {              // d_out (layer 3) or null
  const int pos0 = blockIdx.x * 8;           // 512 blocks
  const int h = pos0 >> 6, wb = pos0 & 63;
  const int t = threadIdx.x, lane = t & 63, wv = t >> 6;

  __shared__ float4 s_cw[9][8];
  __shared__ int4   s_ci[9][8];
  __shared__ float  sO[8][260];

  if (t < 72) {
    const int k = t >> 3, m = t & 7;
    const int ky = k / 3 - 1, kx = k % 3 - 1;
    const int pos = pos0 + m;
    const float dy = offs[(b * 18 + 2 * k) * HW + pos];
    const float dx = offs[(b * 18 + 2 * k + 1) * HW + pos];
    const float py = (float)(h + ky) + dy;
    const float px = (float)(wb + m + kx) + dx;
    const float y0f = floorf(py), x0f = floorf(px);
    const float wy = py - y0f, wx = px - x0f;
    const int y0 = (int)y0f, x0 = (int)x0f;
    float cw[4]; int ci[4];
#pragma unroll
    for (int j = 0; j < 4; ++j) {
      const int yi = y0 + (j >> 1), xi = x0 + (j & 1);
      const bool v = (yi >= 0) && (yi < 64) && (xi >= 0) && (xi < 64);
      const float wgt = ((j >> 1) ? wy : 1.f - wy) * ((j & 1) ? wx : 1.f - wx);
      cw[j] = v ? wgt : 0.f;
      const int yc = yi < 0 ? 0 : (yi > 63 ? 63 : yi);
      const int xc = xi < 0 ? 0 : (xi > 63 ? 63 : xi);
      ci[j] = yc * 64 + xc;
    }
    s_cw[k][m] = (float4){cw[0], cw[1], cw[2], cw[3]};
    s_ci[k][m] = (int4){ci[0], ci[1], ci[2], ci[3]};
  }
  __syncthreads();

  const int n0 = lane * 4;
#pragma unroll
  for (int p = 0; p < 2; ++p) {
    const int pl = wv * 2 + p;
    float a0 = 0.f, a1 = 0.f, a2 = 0.f, a3 = 0.f;
#pragma unroll
    for (int k = 0; k < 9; ++k) {
      const float4 cw = s_cw[k][pl];
      const int4 ci = s_ci[k][pl];
      {
        const uint2 hv = *(const uint2*)(pvh + ((size_t)ci.x * 9 + k) * 256 + n0);
        a0 = fmaf(cw.x, bf_lo_f(hv.x), a0);
        a1 = fmaf(cw.x, bf_hi_f32(hv.x), a1);
        a2 = fmaf(cw.x, bf_lo_f(hv.y), a2);
        a3 = fmaf(cw.x, bf_hi_f32(hv.y), a3);
      }
      {
        const uint2 hv = *(const uint2*)(pvh + ((size_t)ci.y * 9 + k) * 256 + n0);
        a0 = fmaf(cw.y, bf_lo_f(hv.x), a0);
        a1 = fmaf(cw.y, bf_hi_f32(hv.x), a1);
        a2 = fmaf(cw.y, bf_lo_f(hv.y), a2);
        a3 = fmaf(cw.y, bf_hi_f32(hv.y), a3);
      }
      {
        const uint2 hv = *(const uint2*)(pvh + ((size_t)ci.z * 9 + k) * 256 + n0);
        a0 = fmaf(cw.z, bf_lo_f(hv.x), a0);
        a1 = fmaf(cw.z, bf_hi_f32(hv.x), a1);
        a2 = fmaf(cw.z, bf_lo_f(hv.y), a2);
        a3 = fmaf(cw.z, bf_hi_f32(hv.y), a3);
      }
      {
        const uint2 hv = *(const uint2*)(pvh + ((size_t)ci.w * 9 + k) * 256 + n0);
        a0 = fmaf(cw.w, bf_lo_f(hv.x), a0);
        a1 = fmaf(cw.w, bf_hi_f32(hv.x), a1);
        a2 = fmaf(cw.w, bf_lo_f(hv.y), a2);
        a3 = fmaf(cw.w, bf_hi_f32(hv.y), a3);
      }
    }
    a0 = fmaxf(a0, 0.f); a1 = fmaxf(a1, 0.f);
    a2 = fmaxf(a2, 0.f); a3 = fmaxf(a3, 0.f);
    if (outf) {
      sO[pl][n0] = a0; sO[pl][n0 + 1] = a1;
      sO[pl][n0 + 2] = a2; sO[pl][n0 + 3] = a3;
    } else {
      ushort4 v;
      v.x = (unsigned short)f2bf_bits(a0);
      v.y = (unsigned short)f2bf_bits(a1);
      v.z = (unsigned short)f2bf_bits(a2);
      v.w = (unsigned short)f2bf_bits(a3);
      *(ushort4*)(yplane + (size_t)(pos0 + pl) * 256 + n0) = v;
    }
  }
  if (outf) {
    __syncthreads();
    // NCHW: out[b][n][pos0 + pq*4 .. +4], thread t = n, pq = i
#pragma unroll
    for (int i = 0; i < 2; ++i) {
      float4 vv;
      vv.x = sO[i * 4 + 0][t];
      vv.y = sO[i * 4 + 1][t];
      vv.z = sO[i * 4 + 2][t];
      vv.w = sO[i * 4 + 3][t];
      *(float4*)&outf[(size_t)(b * 256 + t) * HW + pos0 + i * 4] = vv;
    }
  }
}

extern "C" void kernel_launch(void* const* d_in, const int* in_sizes, int n_in,
                              void* d_out, int out_size, void* d_ws, size_t ws_size,
                              hipStream_t stream) {
  const float* x0   = (const float*)d_in[0];  // [4][256][64][64]
  const float* offw = (const float*)d_in[1];  // [4][18][256][3][3]
  const float* offb = (const float*)d_in[2];  // [4][18]
  const float* w    = (const float*)d_in[3];  // [4][256][256][3][3]
  float* out = (float*)d_out;                 // [4][256][64][64]
  float* ws  = (float*)d_ws;

  float* offs = ws;                                     //   294,912 floats
  unsigned short* wph  = (unsigned short*)(ws + 294912);    // 2,359,296 ushort
  unsigned short* owph = wph + 2359296;                     //   294,912 ushort
  unsigned short* xT   = owph + 294912;                     // 4,194,304 ushort
  unsigned short* pvh  = xT + 4194304;                      // 9,437,184 ushort

  wpack_kernel<<<9216, 256, 0, stream>>>(w, wph);
  offwpack_kernel<<<1152, 256, 0, stream>>>(offw, owph);
  xpose_kernel<<<dim3(64, 4, 4), 256, 0, stream>>>(x0, xT);

  for (int r = 0; r < 4; ++r) {
    offconv_mfma<<<512, 256, 0, stream>>>(xT, owph + r * 73728,
                                          offb + r * 18, offs);
    for (int b = 0; b < 4; ++b) {
      unsigned short* plane_b = xT + (size_t)b * HW * 256;
      pvgemm_kernel<<<dim3(18, 64), 256, 0, stream>>>(
          plane_b, wph + (size_t)r * 589824, pvh);
      combine_kernel<<<512, 256, 0, stream>>>(
          pvh, offs, b,
          (r < 3) ? plane_b : nullptr,
          (r < 3) ? nullptr : out);
    }
  }
}

// Round 10
// 520.778 us; speedup vs baseline: 1.3452x; 1.3452x over previous
//
#include <hip/hip_runtime.h>

// RepetHead: 4 layers of (3x3 offset conv -> DCNv1 deform conv -> ReLU)
// B=4, C=256, H=W=64, K=9 taps.
// Round 10: r9's linearity decomposition (PV GEMM + streaming combine) with
// FULL-BATCH dispatches (r9 regression = 32 small serialized per-b launches):
//   PV[b][pos][k][n] = sum_c w[n][k][c] * x[b][pos][c]   (one GEMM dispatch)
//   out[b][pos][n] = relu(sum_{k,j} cw[b,k,pos,j] * PV[b][ci[b,k,pos,j]][k][n])
// ws is 256 MiB (measured from harness poison WRITE_SIZE) -> PV for all 4 b.
// 3 dispatches per layer; 15 total.
//
// ws layout (floats):
//   offs :    294,912
//   wph  :  1,179,648  (2,359,296 ushort, deform B frag-packed, bf16-hi)
//   owph :    147,456  (  294,912 ushort, offset-conv B frag-packed)
//   xT   :  2,097,152  (4,194,304 ushort, activation plane, updated in place)
//   pvh  : 18,874,368  (37,748,736 ushort, PV[4][4096][9][256] bf16-hi)
// total 22,593,536 floats = 90.4 MB (<= 256 MiB)

#define HW 4096

typedef __attribute__((ext_vector_type(8))) __bf16 bf16x8;
typedef __attribute__((ext_vector_type(4))) float f32x4;
typedef __attribute__((ext_vector_type(8))) unsigned short u16x8;

__device__ inline unsigned int f2bf_bits(float f) {
  unsigned int u = __float_as_uint(f);
  return (u + 0x7fffu + ((u >> 16) & 1u)) >> 16;   // RNE to bf16
}
__device__ inline float bf_lo_f(unsigned int w) {   // low ushort -> fp32
  return __uint_as_float(w << 16);
}
__device__ inline float bf_hi_f32(unsigned int w) { // high ushort -> fp32
  return __uint_as_float(w & 0xffff0000u);
}

// ---------------------------------------------------------------------------
// w[r][o][c][ky][kx] -> frag-packed wph[r][q=72][nt=16][lane=64][j=8] (bf16-hi)
// n = nt*16+(lane&15); kk = q*32+(lane>>4)*8+j; c = kk&255; k = kk>>8.
__global__ __launch_bounds__(256) void wpack_kernel(
    const float* __restrict__ w, unsigned short* __restrict__ wph) {
  const int f = blockIdx.x * 256 + threadIdx.x;   // < 2,359,296
  const int j  = f & 7;
  const int l  = (f >> 3) & 63;
  const int nt = (f >> 9) & 15;
  const int q  = (f >> 13) % 72;
  const int r  = f / 589824;
  const int n  = nt * 16 + (l & 15);
  const int kk = q * 32 + ((l >> 4) << 3) + j;
  const int c  = kk & 255, k = kk >> 8;
  wph[f] = (unsigned short)f2bf_bits(w[((r * 256 + n) * 256 + c) * 9 + k]);
}

// offw[r][18][256][3][3] -> owph[r][q=72][nt=2][lane=64][j=8] (n>=18 -> 0)
__global__ __launch_bounds__(256) void offwpack_kernel(
    const float* __restrict__ offw, unsigned short* __restrict__ owph) {
  const int f = blockIdx.x * 256 + threadIdx.x;   // < 294,912
  const int j  = f & 7;
  const int l  = (f >> 3) & 63;
  const int nt = (f >> 9) & 1;
  const int q  = (f >> 10) % 72;
  const int r  = f / 73728;
  const int n  = nt * 16 + (l & 15);
  const int kk = q * 32 + ((l >> 4) << 3) + j;
  const int c  = kk & 255, k = kk >> 8;
  const float v = (n < 18) ? offw[((r * 18 + n) * 256 + c) * 9 + k] : 0.f;
  owph[f] = (unsigned short)f2bf_bits(v);
}

// ---------------------------------------------------------------------------
// x [4][256][4096] fp32 -> xT [4][4096][256] bf16-hi (transpose + cast)
__global__ __launch_bounds__(256) void xpose_kernel(
    const float* __restrict__ x, unsigned short* __restrict__ xh) {
  const int p0 = blockIdx.x * 64;     // pos tile
  const int c0 = blockIdx.y * 64;     // channel tile
  const int b  = blockIdx.z;
  __shared__ float sT[64][65];
  const int t = threadIdx.x;
  const int pj = t & 63, ci0 = (t >> 6) * 16;
  const float* __restrict__ xb = x + ((size_t)(b * 256 + c0)) * HW + p0;
#pragma unroll
  for (int u = 0; u < 16; ++u)
    sT[ci0 + u][pj] = xb[(size_t)(ci0 + u) * HW + pj];
  __syncthreads();
  const int pr = t >> 2, cs = (t & 3) * 16;
  u16x8 va, vb;
#pragma unroll
  for (int u = 0; u < 8; ++u) va[u] = (unsigned short)f2bf_bits(sT[cs + u][pr]);
#pragma unroll
  for (int u = 0; u < 8; ++u) vb[u] = (unsigned short)f2bf_bits(sT[cs + 8 + u][pr]);
  const size_t o = ((size_t)b * HW + p0 + pr) * 256 + c0 + cs;
  *(u16x8*)(xh + o) = va;
  *(u16x8*)(xh + o + 8) = vb;
}

// ---------------------------------------------------------------------------
// Offset conv, zero-LDS MFMA (r4-proven). block = 32m x 32n, 4 waves.
__global__ __launch_bounds__(256) void offconv_mfma(
    const unsigned short* __restrict__ xh,
    const unsigned short* __restrict__ owh,
    const float* __restrict__ bias, float* __restrict__ offs) {
  const int gid = blockIdx.x;                 // 0..511
  const int b = (gid & 7) >> 1;
  const int idx = ((gid >> 3) << 1) | (gid & 1);   // 0..127
  const int h = idx >> 1, w0 = (idx & 1) << 5;
  const int t = threadIdx.x, lane = t & 63, wv = t >> 6;
  const int frow = lane & 15, fgrp = lane >> 4;
  const int mt = wv & 1, nt = wv >> 1;
  const int m = w0 + mt * 16 + frow;          // w coordinate of A row

  f32x4 acc = {0.f, 0.f, 0.f, 0.f};
  const u16x8 z8 = {};
  const size_t xb = (size_t)b * HW;

  for (int k = 0; k < 9; ++k) {
    const int ky = k / 3 - 1, kx = k % 3 - 1;
    if ((unsigned)(h + ky) >= 64u) continue;  // block-uniform: tap row is 0
    const bool vpx = (unsigned)(m + kx) < 64u;
    const int cpx = (m + kx) < 0 ? 0 : ((m + kx) > 63 ? 63 : (m + kx));
    const size_t abase = (xb + (size_t)((h + ky) * 64 + cpx)) * 256 + fgrp * 8;
#pragma unroll
    for (int cc = 0; cc < 8; ++cc) {
      const int q = k * 8 + cc;
      u16x8 ahr = *(const u16x8*)(xh + abase + cc * 32);
      if (!vpx) ahr = z8;
      const u16x8 bhr = ((const u16x8*)owh)[(q * 2 + nt) * 64 + lane];
      const bf16x8 ah = __builtin_bit_cast(bf16x8, ahr);
      const bf16x8 bh = __builtin_bit_cast(bf16x8, bhr);
      acc = __builtin_amdgcn_mfma_f32_16x16x32_bf16(ah, bh, acc, 0, 0, 0);
    }
  }
  const int oc = nt * 16 + frow;              // C/D: col = lane&15 -> n
  if (oc < 18) {
    const float bv = bias[oc];
    const int wbase = w0 + mt * 16 + fgrp * 4;  // C/D: row = (lane>>4)*4 + r
    float* __restrict__ op = offs + (size_t)(b * 18 + oc) * HW + h * 64 + wbase;
#pragma unroll
    for (int r = 0; r < 4; ++r) op[r] = acc[r] + bv;
  }
}

// ---------------------------------------------------------------------------
// PV GEMM (all b): PV[b][pos][k][n] = sum_c x[b][pos][c] * w[n][k][c].
// grid (18, 32, 4): x -> (k, n-half), y -> 128-pos tile, z -> b.
// Wave = 32 pos (2 m-tiles) x 128 n: 8 chunks x (2 A loads + 8 B loads +
// 16 MFMA). Zero LDS, zero per-chunk VALU, literal indices throughout.
__global__ __launch_bounds__(256) void pvgemm_kernel(
    const unsigned short* __restrict__ xh,   // [4][4096][256] bf16-hi
    const unsigned short* __restrict__ wph,  // this layer, [72][16][64][8]
    unsigned short* __restrict__ pvh) {      // [4][4096][9][256] bf16-hi
  const int nb = blockIdx.x;                 // 0..17
  const int pt = blockIdx.y;                 // 0..31
  const int b  = blockIdx.z;
  const int k = nb >> 1, half = nb & 1;
  const int t = threadIdx.x, lane = t & 63, wv = t >> 6;
  const int frow = lane & 15, quad = lane >> 4;
  const int pos0 = pt * 128 + wv * 32;

  f32x4 acc[2][8];
#pragma unroll
  for (int mt = 0; mt < 2; ++mt)
#pragma unroll
    for (int nt = 0; nt < 8; ++nt) acc[mt][nt] = (f32x4){0.f, 0.f, 0.f, 0.f};

  const unsigned short* __restrict__ xb = xh + (size_t)b * HW * 256;
  const unsigned short* __restrict__ ap0 =
      xb + (size_t)(pos0 + frow) * 256 + quad * 8;
  const unsigned short* __restrict__ ap1 = ap0 + 16 * 256;
  const u16x8* __restrict__ wp = (const u16x8*)wph;
  const int qb = k * 8;

#pragma unroll
  for (int cc = 0; cc < 8; ++cc) {
    const bf16x8 a0 = __builtin_bit_cast(bf16x8, *(const u16x8*)(ap0 + cc * 32));
    const bf16x8 a1 = __builtin_bit_cast(bf16x8, *(const u16x8*)(ap1 + cc * 32));
#pragma unroll
    for (int nt = 0; nt < 8; ++nt) {
      const bf16x8 bv = __builtin_bit_cast(
          bf16x8, wp[((qb + cc) * 16 + half * 8 + nt) * 64 + lane]);
      acc[0][nt] = __builtin_amdgcn_mfma_f32_16x16x32_bf16(a0, bv, acc[0][nt], 0, 0, 0);
      acc[1][nt] = __builtin_amdgcn_mfma_f32_16x16x32_bf16(a1, bv, acc[1][nt], 0, 0, 0);
    }
  }
  // epilogue: C/D row = quad*4+r -> pos, col = frow -> n (within tile)
  unsigned short* __restrict__ pvb = pvh + (size_t)b * HW * 9 * 256;
#pragma unroll
  for (int mt = 0; mt < 2; ++mt)
#pragma unroll
    for (int nt = 0; nt < 8; ++nt)
#pragma unroll
      for (int r = 0; r < 4; ++r) {
        const int pos = pos0 + mt * 16 + quad * 4 + r;
        pvb[((size_t)pos * 9 + k) * 256 + half * 128 + nt * 16 + frow] =
            (unsigned short)f2bf_bits(acc[mt][nt][r]);
      }
}

// ---------------------------------------------------------------------------
// Combine (all b): out[b][pos][n] = relu(sum_k sum_j cw * PV[ci][k][n]).
// grid (512, 4). Block = 8 positions; thread owns 1 pos x 8 n (uint4 loads).
// Layers 0-2: writes the activation plane IN PLACE ([pos][n] bf16-hi).
// Layer 3: fp32 NCHW to d_out via LDS transpose.
__global__ __launch_bounds__(256) void combine_kernel(
    const unsigned short* __restrict__ pvh,  // [4][4096][9][256]
    const float* __restrict__ offs,          // [4][18][4096]
    unsigned short* __restrict__ yplane,     // xT base (layers 0-2) or null
    float* __restrict__ outf) {              // d_out (layer 3) or null
  const int pos0 = blockIdx.x * 8;
  const int b = blockIdx.y;
  const int h = pos0 >> 6, wb = pos0 & 63;
  const int t = threadIdx.x, lane = t & 63, wv = t >> 6;

  __shared__ float4 s_cw[9][8];
  __shared__ int4   s_ci[9][8];
  __shared__ float  sO[8][264];

  if (t < 72) {
    const int k = t >> 3, m = t & 7;
    const int ky = k / 3 - 1, kx = k % 3 - 1;
    const int pos = pos0 + m;
    const float dy = offs[(b * 18 + 2 * k) * HW + pos];
    const float dx = offs[(b * 18 + 2 * k + 1) * HW + pos];
    const float py = (float)(h + ky) + dy;
    const float px = (float)(wb + m + kx) + dx;
    const float y0f = floorf(py), x0f = floorf(px);
    const float wy = py - y0f, wx = px - x0f;
    const int y0 = (int)y0f, x0 = (int)x0f;
    float cw[4]; int ci[4];
#pragma unroll
    for (int j = 0; j < 4; ++j) {
      const int yi = y0 + (j >> 1), xi = x0 + (j & 1);
      const bool v = (yi >= 0) && (yi < 64) && (xi >= 0) && (xi < 64);
      const float wgt = ((j >> 1) ? wy : 1.f - wy) * ((j & 1) ? wx : 1.f - wx);
      cw[j] = v ? wgt : 0.f;
      const int yc = yi < 0 ? 0 : (yi > 63 ? 63 : yi);
      const int xc = xi < 0 ? 0 : (xi > 63 ? 63 : xi);
      ci[j] = yc * 64 + xc;
    }
    s_cw[k][m] = (float4){cw[0], cw[1], cw[2], cw[3]};
    s_ci[k][m] = (int4){ci[0], ci[1], ci[2], ci[3]};
  }
  __syncthreads();

  const unsigned short* __restrict__ pvb = pvh + (size_t)b * HW * 9 * 256;
  const int pl = wv * 2 + (lane >> 5);       // 0..7 position within block
  const int n0 = (lane & 31) * 8;            // 8 n per thread
  float a0 = 0.f, a1 = 0.f, a2 = 0.f, a3 = 0.f;
  float a4 = 0.f, a5 = 0.f, a6 = 0.f, a7 = 0.f;

#define ACC_CORNER(cwv, civ)                                                \
  {                                                                         \
    const uint4 hv = *(const uint4*)(pvb + ((size_t)(civ) * 9 + k) * 256 + n0); \
    a0 = fmaf(cwv, bf_lo_f(hv.x), a0); a1 = fmaf(cwv, bf_hi_f32(hv.x), a1); \
    a2 = fmaf(cwv, bf_lo_f(hv.y), a2); a3 = fmaf(cwv, bf_hi_f32(hv.y), a3); \
    a4 = fmaf(cwv, bf_lo_f(hv.z), a4); a5 = fmaf(cwv, bf_hi_f32(hv.z), a5); \
    a6 = fmaf(cwv, bf_lo_f(hv.w), a6); a7 = fmaf(cwv, bf_hi_f32(hv.w), a7); \
  }
#pragma unroll
  for (int k = 0; k < 9; ++k) {
    const float4 cw = s_cw[k][pl];
    const int4 ci = s_ci[k][pl];
    ACC_CORNER(cw.x, ci.x)
    ACC_CORNER(cw.y, ci.y)
    ACC_CORNER(cw.z, ci.z)
    ACC_CORNER(cw.w, ci.w)
  }
#undef ACC_CORNER
  a0 = fmaxf(a0, 0.f); a1 = fmaxf(a1, 0.f);
  a2 = fmaxf(a2, 0.f); a3 = fmaxf(a3, 0.f);
  a4 = fmaxf(a4, 0.f); a5 = fmaxf(a5, 0.f);
  a6 = fmaxf(a6, 0.f); a7 = fmaxf(a7, 0.f);

  if (outf) {
    float* sr = &sO[pl][n0];
    sr[0] = a0; sr[1] = a1; sr[2] = a2; sr[3] = a3;
    sr[4] = a4; sr[5] = a5; sr[6] = a6; sr[7] = a7;
    __syncthreads();
    // NCHW: thread t = channel n; 8 consecutive positions as two float4
#pragma unroll
    for (int i = 0; i < 2; ++i) {
      float4 vv;
      vv.x = sO[i * 4 + 0][t];
      vv.y = sO[i * 4 + 1][t];
      vv.z = sO[i * 4 + 2][t];
      vv.w = sO[i * 4 + 3][t];
      *(float4*)&outf[(size_t)(b * 256 + t) * HW + pos0 + i * 4] = vv;
    }
  } else {
    u16x8 v;
    v[0] = (unsigned short)f2bf_bits(a0);
    v[1] = (unsigned short)f2bf_bits(a1);
    v[2] = (unsigned short)f2bf_bits(a2);
    v[3] = (unsigned short)f2bf_bits(a3);
    v[4] = (unsigned short)f2bf_bits(a4);
    v[5] = (unsigned short)f2bf_bits(a5);
    v[6] = (unsigned short)f2bf_bits(a6);
    v[7] = (unsigned short)f2bf_bits(a7);
    *(u16x8*)(yplane + ((size_t)b * HW + pos0 + pl) * 256 + n0) = v;
  }
}

extern "C" void kernel_launch(void* const* d_in, const int* in_sizes, int n_in,
                              void* d_out, int out_size, void* d_ws, size_t ws_size,
                              hipStream_t stream) {
  const float* x0   = (const float*)d_in[0];  // [4][256][64][64]
  const float* offw = (const float*)d_in[1];  // [4][18][256][3][3]
  const float* offb = (const float*)d_in[2];  // [4][18]
  const float* w    = (const float*)d_in[3];  // [4][256][256][3][3]
  float* out = (float*)d_out;                 // [4][256][64][64]
  float* ws  = (float*)d_ws;

  float* offs = ws;                                     //   294,912 floats
  unsigned short* wph  = (unsigned short*)(ws + 294912);    // 2,359,296 ushort
  unsigned short* owph = wph + 2359296;                     //   294,912 ushort
  unsigned short* xT   = owph + 294912;                     // 4,194,304 ushort
  unsigned short* pvh  = xT + 4194304;                      // 37,748,736 ushort

  wpack_kernel<<<9216, 256, 0, stream>>>(w, wph);
  offwpack_kernel<<<1152, 256, 0, stream>>>(offw, owph);
  xpose_kernel<<<dim3(64, 4, 4), 256, 0, stream>>>(x0, xT);

  for (int r = 0; r < 4; ++r) {
    offconv_mfma<<<512, 256, 0, stream>>>(xT, owph + r * 73728,
                                          offb + r * 18, offs);
    pvgemm_kernel<<<dim3(18, 32, 4), 256, 0, stream>>>(
        xT, wph + (size_t)r * 589824, pvh);
    combine_kernel<<<dim3(512, 4), 256, 0, stream>>>(
        pvh, offs,
        (r < 3) ? xT : nullptr,
        (r < 3) ? nullptr : out);
  }
}